// Round 5
// baseline (468.461 us; speedup 1.0000x reference)
//
#include <hip/hip_runtime.h>
#include <math.h>

// GMM per-pixel sampling: out = mu[k] + exp(log_std[k]) * eps,
// k = #(cdf < u), cdf = cumsum(softmax(pi_logits)) over K=10 (innermost).
// Shapes [B,F,T,K] = [16,256,1024,10]; rows are 40 B.
//
// R7 structure: PERSISTENT BLOCKS + DOUBLE-BUFFERED DMA PIPELINE (counted
// vmcnt, never drained in steady state). History: R2-R6 varied access
// pattern (divergent vs coalesced), staging (regs vs LDS vs DMA), occupancy
// (25-81%) -- ALL pinned at ~155-165 us with VALU ~22% / HBM ~27%. The one
// invariant was the phase convoy: every wave drains vmcnt(0) before compute,
// so each block alternates memory-idle / VALU-idle. R7 keeps tiles always in
// flight:
//  - 512 blocks (2/CU), each owns a contiguous chunk of 32 tiles.
//  - Tile = 128 row-pairs. Per-tile LDS buffer 32 KiB: [pi 640 f4][mu 640]
//    [ls 640][u 64][e 64]. Two buffers = 64 KiB/block, 2 blocks/CU.
//  - Per tile: issue 19 DMAs (global_load_lds) for tile t+1 into the other
//    buffer, then s_waitcnt vmcnt(19) == "wait for tile t only, keep t+1 in
//    flight" (T4); raw s_barrier (NOT __syncthreads -- that emits vmcnt(0));
//    compute tile t; barrier. u/eps are DMA'd too (4 B ops) so EVERY VMEM op
//    is a builtin -> vmcnt counts are exact. Only the out store is a
//    compiler memory op (older than the counted window; harmless).
//  - sched_barrier(0) fences around compute: ds_reads must not hoist above
//    the barrier (cross-wave DMA dependency) (rule #18-adjacent).
//  - ds_read_b128 at stride-80: lanes l, l+8 alias banks (20*8 mod 32 == 0)
//    -> 2-way per 16-lane phase = free (m136). Gathers/u-reads ~conflict-free.
//  - DMA dest = wave-uniform base + lane*size (linear-dest rule, m104). ✓
//  - Assumes npairs % 128 == 0 (holds: 2,097,152 = 16384 * 128).
//
// Numerics mirror the JAX reference op-for-op (identical to passing R2-R6):
// e_j = expf(l_j - max); S = sum(e) in order; cdf += e_j / S (per-element
// IEEE divide, no hoisted reciprocal); strict cdf < u; k clipped to K-1.

#define KMIX 10
#define TPB 128                 // 2 waves per block
#define F4_ARR 640              // float4 per array per tile (128 pairs * 80 B)
#define F4_U 64                 // float4 per u/e lane-array per tile (1 KiB)
#define F4_TILE 2048            // 3*640 + 2*64 = 2048 f4 = 32 KiB per buffer
#define NBLOCKS 512             // 2 blocks per CU

__device__ __forceinline__ void dma16(const float4* g, float4* l) {
    __builtin_amdgcn_global_load_lds(
        (const __attribute__((address_space(1))) void*)g,
        (__attribute__((address_space(3))) void*)l, 16, 0, 0);
}

__device__ __forceinline__ void dma4(const float* g, float* l) {
    __builtin_amdgcn_global_load_lds(
        (const __attribute__((address_space(1))) void*)g,
        (__attribute__((address_space(3))) void*)l, 4, 0, 0);
}

__device__ __forceinline__ int compute_k(const float* lt, float uval) {
    float m = lt[0];
    #pragma unroll
    for (int j = 1; j < KMIX; ++j) m = fmaxf(m, lt[j]);

    float e[KMIX];
    float S = 0.f;
    #pragma unroll
    for (int j = 0; j < KMIX; ++j) {
        e[j] = expf(lt[j] - m);
        S += e[j];
    }

    float cdf = 0.f;
    int k = 0;
    #pragma unroll
    for (int j = 0; j < KMIX; ++j) {
        cdf += e[j] / S;            // per-element IEEE divide, matches reference
        k += (cdf < uval) ? 1 : 0;  // strict compare, matches reference
    }
    return (k > KMIX - 1) ? (KMIX - 1) : k;   // jnp.clip(k, 0, K-1)
}

// Issue the 19 DMA ops staging tile t into LDS buffer `buf`.
// Order and count are load-bearing: the main loop's s_waitcnt vmcnt(19)
// treats exactly these 19 as "the newest, still-allowed-in-flight" set.
__device__ __forceinline__ void stage_tile(
    const float4* __restrict__ gpi, const float4* __restrict__ gmu,
    const float4* __restrict__ gls, const float* __restrict__ gu,
    const float* __restrict__ ge, long t, float4* buf, int tid)
{
    const float4* p = gpi + t * F4_ARR;
    const float4* m = gmu + t * F4_ARR;
    const float4* s = gls + t * F4_ARR;
    #pragma unroll
    for (int j = 0; j < 5; ++j) dma16(p + j * TPB + tid, buf + j * TPB + tid);
    #pragma unroll
    for (int j = 0; j < 5; ++j) dma16(m + j * TPB + tid, buf + F4_ARR + j * TPB + tid);
    #pragma unroll
    for (int j = 0; j < 5; ++j) dma16(s + j * TPB + tid, buf + 2 * F4_ARR + j * TPB + tid);

    const float* u = gu + t * (2 * TPB);
    const float* e = ge + t * (2 * TPB);
    float* su = reinterpret_cast<float*>(buf + 3 * F4_ARR);
    float* se = reinterpret_cast<float*>(buf + 3 * F4_ARR + F4_U);
    #pragma unroll
    for (int j = 0; j < 2; ++j) dma4(u + j * TPB + tid, su + j * TPB + tid);
    #pragma unroll
    for (int j = 0; j < 2; ++j) dma4(e + j * TPB + tid, se + j * TPB + tid);
}

__device__ __forceinline__ void compute_tile(const float4* buf, long t,
                                             float* __restrict__ out, int tid)
{
    // Own row-pair: 80 B = 5 x ds_read_b128 at stride-80 (2-way, free).
    float l[2 * KMIX];
    #pragma unroll
    for (int j = 0; j < 5; ++j) {
        float4 a = buf[tid * 5 + j];
        l[4 * j + 0] = a.x; l[4 * j + 1] = a.y;
        l[4 * j + 2] = a.z; l[4 * j + 3] = a.w;
    }
    const float2* su2 = reinterpret_cast<const float2*>(buf + 3 * F4_ARR);
    const float2* se2 = reinterpret_cast<const float2*>(buf + 3 * F4_ARR + F4_U);
    float2 uu = su2[tid];
    float2 ee = se2[tid];

    int k0 = compute_k(l, uu.x);
    int k1 = compute_k(l + KMIX, uu.y);

    const float* smu = reinterpret_cast<const float*>(buf + F4_ARR);
    const float* sls = reinterpret_cast<const float*>(buf + 2 * F4_ARR);
    float mk0 = smu[20 * tid + k0];
    float sk0 = sls[20 * tid + k0];
    float mk1 = smu[20 * tid + KMIX + k1];
    float sk1 = sls[20 * tid + KMIX + k1];

    float2 r;
    r.x = mk0 + expf(sk0) * ee.x;
    r.y = mk1 + expf(sk1) * ee.y;
    reinterpret_cast<float2*>(out)[t * TPB + tid] = r;
}

__global__ __launch_bounds__(TPB, 1) void gmm_sample_kernel(
    const float* __restrict__ mu,
    const float* __restrict__ log_std,
    const float* __restrict__ pi_logits,
    const float* __restrict__ u_cat,
    const float* __restrict__ eps,
    float* __restrict__ out,
    int ntiles)
{
    __shared__ float4 lds4[2 * F4_TILE];     // 64 KiB -> 2 blocks/CU

    const int tid = threadIdx.x;
    const int tpbk = (ntiles + gridDim.x - 1) / gridDim.x;
    long t0 = (long)blockIdx.x * tpbk;
    long tend = t0 + tpbk;
    if (tend > ntiles) tend = ntiles;
    if (t0 >= tend) return;

    const float4* gpi = reinterpret_cast<const float4*>(pi_logits);
    const float4* gmu = reinterpret_cast<const float4*>(mu);
    const float4* gls = reinterpret_cast<const float4*>(log_std);

    float4* buf0 = lds4;
    float4* buf1 = lds4 + F4_TILE;

    // Prologue: stage first tile; no drain here -- the first loop
    // iteration's counted wait covers it.
    stage_tile(gpi, gmu, gls, u_cat, eps, t0, buf0, tid);

    for (long t = t0; t < tend; ++t) {
        float4* bcur = ((t - t0) & 1) ? buf1 : buf0;
        float4* bnxt = ((t - t0) & 1) ? buf0 : buf1;

        if (t + 1 < tend) {
            // Prefetch next tile, then wait for CURRENT tile only:
            // the newest 19 VMEM ops (next tile's DMAs) stay in flight.
            stage_tile(gpi, gmu, gls, u_cat, eps, t + 1, bnxt, tid);
            asm volatile("s_waitcnt vmcnt(19)" ::: "memory");
        } else {
            asm volatile("s_waitcnt vmcnt(0)" ::: "memory");
        }
        __builtin_amdgcn_s_barrier();          // raw barrier: no vmcnt(0) drain
        __builtin_amdgcn_sched_barrier(0);     // pin ds_reads below the barrier

        compute_tile(bcur, t, out, tid);

        __builtin_amdgcn_sched_barrier(0);
        __builtin_amdgcn_s_barrier();          // all waves done reading bcur
        // next iteration DMAs into bcur (as bnxt) only after this point
    }
}

extern "C" void kernel_launch(void* const* d_in, const int* in_sizes, int n_in,
                              void* d_out, int out_size, void* d_ws, size_t ws_size,
                              hipStream_t stream) {
    const float* mu        = (const float*)d_in[0];
    const float* log_std   = (const float*)d_in[1];
    const float* pi_logits = (const float*)d_in[2];
    const float* u_cat     = (const float*)d_in[3];
    const float* eps       = (const float*)d_in[4];
    float* out = (float*)d_out;

    int N = in_sizes[3];              // B*F*T = 4,194,304
    int npairs = N / 2;               // 2,097,152
    int ntiles = npairs / TPB;        // 16,384 (exact: npairs % 128 == 0)
    int grid = (ntiles < NBLOCKS) ? ntiles : NBLOCKS;
    gmm_sample_kernel<<<grid, TPB, 0, stream>>>(mu, log_std, pi_logits,
                                                u_cat, eps, out, ntiles);
}